// Round 18
// baseline (305.303 us; speedup 1.0000x reference)
//
#include <hip/hip_runtime.h>
#include <hip/hip_bf16.h>

#define NB   4
#define FIN  128
#define HH   256
#define WWW  256
#define LLAB 19
#define SSTY 512
#define HW   (HH*WWW)        // 65536
#define NRED (NB*HW)         // 262144

// workspace layout (float offsets)
#define WS_NT   0            // noise transposed [B][H][W]  262144
#define WS_SUM  262144       // 128
#define WS_SSQ  262272       // 128
#define WS_MEAN 262400       // 128
#define WS_ISTD 262528       // 128
#define WS_MU   262656       // 4*19*512 = 38912
#define WS_A2   301568       // 4*19*9*256 = 175104 -> end 476672 floats
// byte offsets
#define WS_BSTG_B 1906688    // [b 4][s 45][16384 B] = 2949120 -> end 4855808
#define WS_WSH_B  4855808    // 20*9*128 bf16 = 46080 B -> end 4901888

// actv2 LDS layout: [cg 16][hp 324] x 16B; stride multiple of 16
#define ASTRIDE 5200

typedef __attribute__((ext_vector_type(8))) short bf16x8;
typedef __attribute__((ext_vector_type(4))) float f32x4;

__device__ inline unsigned short f2bf(float f) {
  __hip_bfloat16 h = __float2bfloat16(f);
  union { __hip_bfloat16 h; unsigned short u; } cv; cv.h = h; return cv.u;
}
__device__ inline float bf2f(short u) {
  union { unsigned int u; float f; } cv;
  cv.u = ((unsigned int)(unsigned short)u) << 16; return cv.f;
}

__device__ inline void gload_lds16(const void* g, void* l) {
  __builtin_amdgcn_global_load_lds(
      (const __attribute__((address_space(1))) void*)g,
      (__attribute__((address_space(3))) void*)l, 16, 0, 0);
}

// ---- kprep1: ntrans (0..255) + mu (256..407) + packmain (408..551)
//      + packsh (552..641) -----------------------------------------------------
__global__ __launch_bounds__(256) void kprep1(const float* __restrict__ noise,
                                              const float* __restrict__ style,
                                              const float* __restrict__ Wfc,
                                              const float* __restrict__ bfc,
                                              const float* __restrict__ w_g,
                                              const float* __restrict__ w_b,
                                              const float* __restrict__ w_sh,
                                              const float* __restrict__ g_blend,
                                              const float* __restrict__ b_blend,
                                              char* __restrict__ wsb,
                                              float* __restrict__ ws) {
  const int t = threadIdx.x;
  if (blockIdx.x < 256) {
    __shared__ float tile[32][33];
    int blk = blockIdx.x;
    int b = blk >> 6, by = (blk >> 3) & 7, bx = blk & 7;
    int w0 = bx * 32, h0 = by * 32;
    int txx = t & 31, tyy = t >> 5;
    #pragma unroll
    for (int j = 0; j < 4; ++j) {
      int wi = w0 + tyy + j * 8;
      tile[tyy + j * 8][txx] = noise[(size_t)(b * 256 + wi) * 256 + h0 + txx];
    }
    __syncthreads();
    #pragma unroll
    for (int j = 0; j < 4; ++j) {
      int hi = h0 + tyy + j * 8;
      ws[WS_NT + (size_t)(b * 256 + hi) * 256 + w0 + txx] = tile[txx][tyy + j * 8];
    }
  } else if (blockIdx.x < 408) {
    int m = blockIdx.x - 256;
    int j = m >> 3, r = m & 7, b = r >> 1, half = r & 1;
    int o = half * 256 + t;
    const float4* wrow = (const float4*)(Wfc + ((size_t)j * 512 + o) * 512);
    const float4* srow = (const float4*)(style + ((size_t)b * 19 + j) * 512);
    float acc = 0.f;
    for (int d = 0; d < 128; ++d) {
      float4 w = wrow[d];
      float4 s = srow[d];
      acc = fmaf(w.x, s.x, acc); acc = fmaf(w.y, s.y, acc);
      acc = fmaf(w.z, s.z, acc); acc = fmaf(w.w, s.w, acc);
    }
    acc += bfc[j * 512 + o];
    ws[WS_MU + ((size_t)b * 19 + j) * 512 + o] = fmaxf(acc, 0.f);
  } else if (blockIdx.x < 552) {
    int tid = (blockIdx.x - 408) * 256 + t;
    int lane = tid & 63, grp = tid >> 6;
    int s36 = grp % 36, nb = grp / 36;
    int kk = s36 >> 2, cb = s36 & 3;
    int n = nb * 16 + (lane & 15);
    int conv = n & 1, cout = n >> 1;
    float blend = conv ? b_blend[0] : g_blend[0];
    float scale = 1.f - 1.f / (1.f + __expf(-blend));
    const float* src = conv ? w_b : w_g;
    bf16x8 v;
    #pragma unroll
    for (int i = 0; i < 8; ++i) {
      int k = s36 * 32 + (lane >> 4) * 8 + i;
      int kki = k >> 7, cin = k & 127;
      v[i] = (short)f2bf(scale * src[((size_t)cout * 128 + cin) * 9 + kki]);
    }
    size_t slot = (size_t)(kk * 5 + cb) * 16384 + (size_t)(nb * 64 + lane) * 16;
    #pragma unroll
    for (int bb2 = 0; bb2 < 4; ++bb2)
      *(bf16x8*)(wsb + WS_BSTG_B + (size_t)bb2 * 45 * 16384 + slot) = v;
  } else {
    int tid = (blockIdx.x - 552) * 256 + t;
    if (tid < 23040) {
      int l = tid / 1152, r = tid % 1152, k = r >> 7, cin = r & 127;
      float v = (l == 0) ? 0.f : w_sh[((size_t)cin * 19 + (l - 1)) * 9 + k];
      ((unsigned short*)(wsb + WS_WSH_B))[tid] = f2bf(v);
    }
  }
}

// ---------------- kprep2: stats (blocks 0..511) + atab (blocks 512..639) -----
__global__ __launch_bounds__(512) void kprep2(const float* __restrict__ x,
                                              const float* __restrict__ nv,
                                              const float* __restrict__ w_cg,
                                              const float* __restrict__ w_cb,
                                              float* __restrict__ ws) {
  const int t = threadIdx.x;
  if (blockIdx.x < 512) {
    const int bc = blockIdx.x;
    const int b = bc >> 7, c = bc & 127;
    const float4* xp = (const float4*)(x + (size_t)bc * HW);
    const float4* np = (const float4*)(ws + WS_NT + (size_t)b * HW);
    const float nvc = nv[c];
    float s1 = 0.f, s2 = 0.f;
    for (int i = 0; i < 32; ++i) {
      float4 xv = xp[i * 512 + t];
      float4 nz = np[i * 512 + t];
      float v0 = xv.x + nvc * nz.x; s1 += v0; s2 = fmaf(v0, v0, s2);
      float v1 = xv.y + nvc * nz.y; s1 += v1; s2 = fmaf(v1, v1, s2);
      float v2 = xv.z + nvc * nz.z; s1 += v2; s2 = fmaf(v2, v2, s2);
      float v3 = xv.w + nvc * nz.w; s1 += v3; s2 = fmaf(v3, v3, s2);
    }
    #pragma unroll
    for (int m = 32; m; m >>= 1) { s1 += __shfl_xor(s1, m); s2 += __shfl_xor(s2, m); }
    if ((t & 63) == 0) { atomicAdd(&ws[WS_SUM + c], s1); atomicAdd(&ws[WS_SSQ + c], s2); }
  } else {
    __shared__ float wlds[32 * 288];
    const int blkm = blockIdx.x - 512;
    const int cblk = blkm & 7, ssplit = (blkm >> 3) & 3, b = blkm >> 5;
    const int conv = t / 144, r = t % 144, cl = r / 9, k = r % 9;
    const int c = cblk * 16 + cl;
    const float* mu = ws + WS_MU;
    float acc[19];
    #pragma unroll
    for (int l = 0; l < 19; ++l) acc[l] = 0.f;

    for (int chunk = 0; chunk < 4; ++chunk) {
      const int s0 = ssplit * 128 + chunk * 32;
      for (int i = t; i < 9216; i += 512) {
        int kx = i % 9, q = i / 9, sl = q & 31, cc = q >> 5;
        int cv2 = cc >> 4, cl2 = cc & 15;
        const float* src = cv2 ? w_cb : w_cg;
        float v = src[((size_t)(cblk * 16 + cl2) * 512 + s0 + sl) * 9 + kx];
        wlds[sl * 288 + cv2 * 144 + cl2 * 9 + kx] = v;
      }
      __syncthreads();
      if (t < 288) {
        for (int sl = 0; sl < 32; ++sl) {
          float w = wlds[sl * 288 + t];
          int s = s0 + sl;
          #pragma unroll
          for (int l = 0; l < 19; ++l)
            acc[l] = fmaf(mu[((size_t)b * 19 + l) * 512 + s], w, acc[l]);
        }
      }
      __syncthreads();
    }
    if (t < 288) {
      #pragma unroll
      for (int l = 0; l < 19; ++l)
        atomicAdd(&ws[WS_A2 + (((size_t)b * 19 + l) * 9 + k) * 256 + conv * 128 + c], acc[l]);
    }
  }
}

// ---- kprep3: packoh (144 blocks) + stats-finalize (block 0) ------------------
__global__ __launch_bounds__(256) void kprep3(const float* __restrict__ g_blend,
                                              const float* __restrict__ b_blend,
                                              char* __restrict__ wsb,
                                              float* __restrict__ ws) {
  if (blockIdx.x == 0 && threadIdx.x < 128) {
    int c = threadIdx.x;
    float mean = ws[WS_SUM + c] / (float)NRED;
    float var = ws[WS_SSQ + c] / (float)NRED - mean * mean;
    ws[WS_MEAN + c] = mean;
    ws[WS_ISTD + c] = 1.f / sqrtf(var + 1e-5f);
  }
  int tid = blockIdx.x * 256 + threadIdx.x;
  int lane = tid & 63, grp = tid >> 6;
  int kk = grp % 9, nb = (grp / 9) % 16, b = grp / 144;
  int n = nb * 16 + (lane & 15);
  int conv = n & 1, cout = n >> 1;
  float blend = conv ? b_blend[0] : g_blend[0];
  float scale = 1.f / (1.f + __expf(-blend));
  bf16x8 v;
  #pragma unroll
  for (int i = 0; i < 8; ++i) {
    int l = (lane >> 4) * 8 + i;
    float val = 0.f;
    if (l < 19)
      val = scale * ws[WS_A2 + (((size_t)b * 19 + l) * 9 + kk) * 256 + conv * 128 + cout];
    v[i] = (short)f2bf(val);
  }
  *(bf16x8*)(wsb + WS_BSTG_B + ((size_t)b * 45 + kk * 5 + 4) * 16384 +
             (size_t)(nb * 64 + lane) * 16) = v;
}

// ---------------- main fused MFMA kernel --------------------------------------
// grid (16,16,4b), block 1024 (16 waves: 4M x 4N). Tile 16x16 px, N=256.
// K=64 phases: 23 phases (22x two K=32 substeps + tail), 2x32KB double-buffer,
// ONE barrier per phase (half of R15's 45). One-hot A built IN REGISTERS
// (ohA LDS eliminated -> dbuf fits). All ds addr = base + imm offset.
// LDS: labt 1600 | actv2 83200 | small 3072 | bstage 65536 = 153408
__global__ __launch_bounds__(1024, 4) void k_main(
    const float* __restrict__ x, const int* __restrict__ labels,
    const float* __restrict__ b_sh,
    const float* __restrict__ b_g, const float* __restrict__ b_b,
    const float* __restrict__ b_cg, const float* __restrict__ b_cb,
    const float* __restrict__ noise_var,
    const float* __restrict__ g_blend, const float* __restrict__ b_blend,
    const float* __restrict__ ws, float* __restrict__ out) {
  extern __shared__ char smem[];
  int* labt = (int*)smem;                    // [20][20]
  char* actv = smem + 1600;                  // [16 cg][324 hp]x16B, stride 5200
  float* gbias = (float*)(smem + 84800);
  float* bbias = gbias + 128; float* nvl = gbias + 256;
  float* meanl = gbias + 384; float* istdl = gbias + 512; float* bshl = gbias + 640;
  char* bstg = smem + 87872;                 // 2 x 32768 double buffer

  const int t = threadIdx.x;
  const int b = blockIdx.z;
  const int y0 = blockIdx.y * 16, x0 = blockIdx.x * 16;
  const char* wsb = (const char*)ws;
  const char* wshp = wsb + WS_WSH_B;

  // ---- phase 1: small arrays, label tile ----
  if (t < 128) {
    float ga = 1.f / (1.f + __expf(-g_blend[0]));
    float ba = 1.f / (1.f + __expf(-b_blend[0]));
    gbias[t] = ga * b_cg[t] + (1.f - ga) * b_g[t];
    bbias[t] = ba * b_cb[t] + (1.f - ba) * b_b[t];
    nvl[t] = noise_var[t];
    meanl[t] = ws[WS_MEAN + t];
    istdl[t] = ws[WS_ISTD + t];
    bshl[t] = b_sh[t];
  }
  if (t < 400) {
    int ly = t / 20, lx = t % 20;
    int gy = y0 - 2 + ly, gx = x0 - 2 + lx;
    int v = 0;
    if ((unsigned)gy < 256u && (unsigned)gx < 256u)
      v = labels[((size_t)(b * 256 + gy)) * 256 + gx] + 1;
    labt[t] = v;
  }
  __syncthreads();

  // ---- phase 2: actv tile ([cg][hp] layout) ----
  for (int it = t; it < 5184; it += 1024) {      // 324 px * 16 cin-groups
    int hp = it >> 4, cg = it & 15;
    int py = hp / 18, px = hp - py * 18;
    int gy = y0 - 1 + py, gx = x0 - 1 + px;
    int baddr = cg * ASTRIDE + hp * 16;
    bf16x8 o = {0, 0, 0, 0, 0, 0, 0, 0};
    if ((unsigned)gy < 256u && (unsigned)gx < 256u) {
      float accv[8];
      #pragma unroll
      for (int j = 0; j < 8; ++j) accv[j] = bshl[cg * 8 + j];
      #pragma unroll
      for (int k = 0; k < 9; ++k) {
        int dy = k / 3, dx = k - 3 * (k / 3);
        int lv = labt[(py + dy) * 20 + (px + dx)];
        bf16x8 wvv = *(const bf16x8*)(wshp + (size_t)((lv * 9 + k) * 128 + cg * 8) * 2);
        #pragma unroll
        for (int j = 0; j < 8; ++j) accv[j] += bf2f(wvv[j]);
      }
      #pragma unroll
      for (int j = 0; j < 8; ++j) o[j] = (short)f2bf(fmaxf(accv[j], 0.f));
    }
    *(bf16x8*)(actv + baddr) = o;
  }
  __syncthreads();   // full drain: vmcnt==0 entering the K-loop

  // ---- phase 3: 23 K=64 phases, 2x32KB dbuf, 1 barrier/phase ----
  const int lane = t & 63;
  const int wid = t >> 6;                     // 0..15
  const int wm = wid & 3, wn = wid >> 2;      // 4 M-waves x 4 N-waves
  const int l15 = lane & 15, l16 = lane >> 4;

  const char* abase  = actv + l16 * ASTRIDE + (wm * 4 * 18 + l15) * 16;
  const char* bbase  = bstg + (wn * 4) * 1024 + lane * 16;
  const char* bsrc = wsb + WS_BSTG_B + (size_t)b * 45 * 16384 + (size_t)t * 16;
  char* ldsd0 = bstg + t * 16;
  char* ldsd1 = ldsd0 + 32768;
  const int lvbase = l16 * 8;

  f32x4 acc[4][4];
  #pragma unroll
  for (int i = 0; i < 4; ++i)
    #pragma unroll
    for (int j = 0; j < 4; ++j) acc[i][j] = (f32x4){0.f, 0.f, 0.f, 0.f};

#define SUB(CB, KY, KX, CUROFF, BO) { \
  bf16x8 bfr_[4]; \
  _Pragma("unroll") \
  for (int nf_ = 0; nf_ < 4; ++nf_) \
    bfr_[nf_] = *(const bf16x8*)(bbase + (CUROFF) + (BO) + nf_ * 1024); \
  _Pragma("unroll") \
  for (int mf_ = 0; mf_ < 4; ++mf_) { \
    bf16x8 af_; \
    if ((CB) < 4) { \
      af_ = *(const bf16x8*)(abase + (CB) * (4 * ASTRIDE) + ((mf_ + (KY)) * 18 + (KX)) * 16); \
    } else { \
      int lv_ = labt[(wm * 4 + mf_ + (KY) + 1) * 20 + l15 + (KX) + 1] - 1; \
      _Pragma("unroll") \
      for (int i_ = 0; i_ < 8; ++i_) \
        af_[i_] = (short)((lvbase + i_ == lv_) ? 0x3F80 : 0); \
    } \
    __builtin_amdgcn_s_setprio(1); \
    _Pragma("unroll") \
    for (int nf_ = 0; nf_ < 4; ++nf_) \
      acc[mf_][nf_] = __builtin_amdgcn_mfma_f32_16x16x32_bf16(af_, bfr_[nf_], acc[mf_][nf_], 0, 0, 0); \
    __builtin_amdgcn_s_setprio(0); \
  } }

#define PH(CB0, KY0, KX0, CB1, KY1, KX1, CUROFF, NXT, SO0, SO1, NST) { \
  asm volatile("s_waitcnt vmcnt(0)" ::: "memory"); \
  __builtin_amdgcn_s_barrier(); \
  __builtin_amdgcn_sched_barrier(0); \
  if ((NST) >= 1) gload_lds16(bsrc + (size_t)(SO0) * 16384, NXT); \
  if ((NST) >= 2) gload_lds16(bsrc + (size_t)(SO1) * 16384, NXT + 16384); \
  SUB(CB0, KY0, KX0, CUROFF, 0) \
  SUB(CB1, KY1, KX1, CUROFF, 16384) \
}

  // prologue: stage s=0,1 -> buf0
  gload_lds16(bsrc, ldsd0);
  gload_lds16(bsrc + 16384, ldsd0 + 16384);

  PH(0,0,0, 1,0,0,     0, ldsd1,  2,  3, 2)  // p0:  s0,1
  PH(2,0,0, 3,0,0, 32768, ldsd0,  4,  5, 2)  // p1:  s2,3
  PH(4,0,0, 0,0,1,     0, ldsd1,  6,  7, 2)  // p2:  s4,5
  PH(1,0,1, 2,0,1, 32768, ldsd0,  8,  9, 2)  // p3:  s6,7
  PH(3,0,1, 4,0,1,     0, ldsd1, 10, 11, 2)  // p4:  s8,9
  PH(0,0,2, 1,0,2, 32768, ldsd0, 12, 13, 2)  // p5:  s10,11
  PH(2,0,2, 3,0,2,     0, ldsd1, 14, 15, 2)  // p6:  s12,13
  PH(4,0,2, 0,1,0, 32768, ldsd0, 16, 17, 2)  // p7:  s14,15
  PH(1,1,0, 2,1,0,     0, ldsd1, 18, 19, 2)  // p8:  s16,17
  PH(3,1,0, 4,1,0, 32768, ldsd0, 20, 21, 2)  // p9:  s18,19
  PH(0,1,1, 1,1,1,     0, ldsd1, 22, 23, 2)  // p10: s20,21
  PH(2,1,1, 3,1,1, 32768, ldsd0, 24, 25, 2)  // p11: s22,23
  PH(4,1,1, 0,1,2,     0, ldsd1, 26, 27, 2)  // p12: s24,25
  PH(1,1,2, 2,1,2, 32768, ldsd0, 28, 29, 2)  // p13: s26,27
  PH(3,1,2, 4,1,2,     0, ldsd1, 30, 31, 2)  // p14: s28,29
  PH(0,2,0, 1,2,0, 32768, ldsd0, 32, 33, 2)  // p15: s30,31
  PH(2,2,0, 3,2,0,     0, ldsd1, 34, 35, 2)  // p16: s32,33
  PH(4,2,0, 0,2,1, 32768, ldsd0, 36, 37, 2)  // p17: s34,35
  PH(1,2,1, 2,2,1,     0, ldsd1, 38, 39, 2)  // p18: s36,37
  PH(3,2,1, 4,2,1, 32768, ldsd0, 40, 41, 2)  // p19: s38,39
  PH(0,2,2, 1,2,2,     0, ldsd1, 42, 43, 2)  // p20: s40,41
  PH(2,2,2, 3,2,2, 32768, ldsd0, 44,  0, 1)  // p21: s42,43 (stage s44 -> buf0)
  // p22: s=44 (OH, kk=8) from buf0 slot 0
  {
    asm volatile("s_waitcnt vmcnt(0)" ::: "memory");
    __builtin_amdgcn_s_barrier();
    __builtin_amdgcn_sched_barrier(0);
    SUB(4, 2, 2, 0, 0)
  }
#undef PH
#undef SUB

  // ---- epilogue: LDS round-trip per chunk, coalesced x/nt/out traffic ----
  const float* nt = ws + WS_NT + (size_t)b * HW;
  float* eps = (float*)(smem + 1600);          // [64][260] f32 chunk

  #pragma unroll
  for (int chunk = 0; chunk < 4; ++chunk) {
    __syncthreads();
    #pragma unroll
    for (int mf = 0; mf < 4; ++mf) {
      int widx = (wn * 16 + l15) * 260 + (wm * 4 + mf) * 16 + l16 * 4;
      *(f32x4*)(eps + widx) = acc[mf][chunk];
    }
    __syncthreads();
    #pragma unroll
    for (int rep = 0; rep < 2; ++rep) {
      int u = rep * 1024 + t;                 // (ci 32)(y 16)(xq 4)
      int xq = u & 3, y = (u >> 2) & 15, ci = u >> 6;
      int wnp = ci >> 3, qq = ci & 7;
      int c = wnp * 32 + chunk * 8 + qq;
      int rg = wnp * 16 + 2 * qq;
      f32x4 g4 = *(const f32x4*)(eps + rg * 260 + y * 16 + xq * 4);
      f32x4 b4 = *(const f32x4*)(eps + (rg + 1) * 260 + y * 16 + xq * 4);
      const float gb_ = gbias[c], bb_ = bbias[c];
      const float mn = meanl[c], is = istdl[c], nv = nvl[c];
      size_t off = (((size_t)(b * 128 + c)) * 256 + (y0 + y)) * 256 + x0 + xq * 4;
      float4 xv = *(const float4*)(x + off);
      float4 nz = *(const float4*)(nt + (y0 + y) * 256 + x0 + xq * 4);
      float4 o;
      o.x = ((xv.x + nv * nz.x) - mn) * is * (1.f + g4[0] + gb_) + (b4[0] + bb_);
      o.y = ((xv.y + nv * nz.y) - mn) * is * (1.f + g4[1] + gb_) + (b4[1] + bb_);
      o.z = ((xv.z + nv * nz.z) - mn) * is * (1.f + g4[2] + gb_) + (b4[2] + bb_);
      o.w = ((xv.w + nv * nz.w) - mn) * is * (1.f + g4[3] + gb_) + (b4[3] + bb_);
      *(float4*)(out + off) = o;
    }
  }
}

extern "C" void kernel_launch(void* const* d_in, const int* in_sizes, int n_in,
                              void* d_out, int out_size, void* d_ws, size_t ws_size,
                              hipStream_t stream) {
  const float* x        = (const float*)d_in[0];
  const int*   labels   = (const int*)d_in[1];
  const float* noise    = (const float*)d_in[2];
  const float* style    = (const float*)d_in[3];
  const float* nvar     = (const float*)d_in[4];
  const float* w_sh     = (const float*)d_in[5];
  const float* b_sh     = (const float*)d_in[6];
  const float* w_g      = (const float*)d_in[7];
  const float* b_g      = (const float*)d_in[8];
  const float* w_b      = (const float*)d_in[9];
  const float* b_b      = (const float*)d_in[10];
  const float* Wfc      = (const float*)d_in[11];
  const float* bfc      = (const float*)d_in[12];
  const float* w_cg     = (const float*)d_in[13];
  const float* b_cg     = (const float*)d_in[14];
  const float* w_cb     = (const float*)d_in[15];
  const float* b_cb     = (const float*)d_in[16];
  const float* g_blend  = (const float*)d_in[17];
  const float* b_blend  = (const float*)d_in[18];
  float* ws  = (float*)d_ws;
  char*  wsb = (char*)d_ws;
  float* out = (float*)d_out;

  static bool attr_set = false;
  if (!attr_set) {
    (void)hipFuncSetAttribute((const void*)k_main,
                              hipFuncAttributeMaxDynamicSharedMemorySize, 153408);
    attr_set = true;
  }

  hipMemsetAsync((char*)d_ws + (size_t)WS_SUM * 4, 0, 256 * 4, stream);
  hipMemsetAsync((char*)d_ws + (size_t)WS_A2 * 4, 0, (size_t)175104 * 4, stream);

  kprep1<<<dim3(642), dim3(256), 0, stream>>>(noise, style, Wfc, bfc,
                                              w_g, w_b, w_sh, g_blend, b_blend,
                                              wsb, ws);
  kprep2<<<dim3(640), dim3(512), 0, stream>>>(x, nvar, w_cg, w_cb, ws);
  kprep3<<<dim3(144), dim3(256), 0, stream>>>(g_blend, b_blend, wsb, ws);
  k_main<<<dim3(16, 16, 4), dim3(1024), 153408, stream>>>(
      x, labels, b_sh, b_g, b_b, b_cg, b_cb,
      nvar, g_blend, b_blend, ws, out);
}

// Round 21
// 288.358 us; speedup vs baseline: 1.0588x; 1.0588x over previous
//
#include <hip/hip_runtime.h>
#include <hip/hip_bf16.h>

#define NB   4
#define FIN  128
#define HH   256
#define WWW  256
#define LLAB 19
#define SSTY 512
#define HW   (HH*WWW)        // 65536
#define NRED (NB*HW)         // 262144

// workspace layout (float offsets)
#define WS_NT   0            // noise transposed [B][H][W]  262144
#define WS_SUM  262144       // 128
#define WS_SSQ  262272       // 128
#define WS_MEAN 262400       // 128
#define WS_ISTD 262528       // 128
#define WS_MU   262656       // 4*19*512 = 38912
#define WS_A2   301568       // 4*19*9*256 = 175104 -> end 476672
#define WS_S1N  476672       // scalar noise sum
#define WS_S2N  476673       // scalar noise sumsq  (gap to float 476688)
// byte offsets  (BSTG starts at float 476688 -> NO overlap with S1N/S2N;
//  R20 bug: BSTG began at byte 1906688 == WS_S1N*4, aliasing the scalars)
#define WS_BSTG_B 1906752    // [b 4][s 45][16384 B] = 2949120 -> end 4855872
#define WS_WSH_B  4855872    // 20*9*128 bf16 = 46080 B -> end 4901952

// actv2 LDS layout: [cg 16][hp 324] x 16B; stride multiple of 16
#define ASTRIDE 5200
#define OHSTRIDE 80

typedef __attribute__((ext_vector_type(8))) short bf16x8;
typedef __attribute__((ext_vector_type(4))) float f32x4;

__device__ inline unsigned short f2bf(float f) {
  __hip_bfloat16 h = __float2bfloat16(f);
  union { __hip_bfloat16 h; unsigned short u; } cv; cv.h = h; return cv.u;
}
__device__ inline float bf2f(short u) {
  union { unsigned int u; float f; } cv;
  cv.u = ((unsigned int)(unsigned short)u) << 16; return cv.f;
}

__device__ inline void gload_lds16(const void* g, void* l) {
  __builtin_amdgcn_global_load_lds(
      (const __attribute__((address_space(1))) void*)g,
      (__attribute__((address_space(3))) void*)l, 16, 0, 0);
}

// ---- kprep1: ntrans(0..255) + mu(256..407) + packmain(408..551)
//      + packsh(552..641) + xstats(642..1153) + nstats(1154..1169) ------------
__global__ __launch_bounds__(256) void kprep1(const float* __restrict__ noise,
                                              const float* __restrict__ style,
                                              const float* __restrict__ Wfc,
                                              const float* __restrict__ bfc,
                                              const float* __restrict__ w_g,
                                              const float* __restrict__ w_b,
                                              const float* __restrict__ w_sh,
                                              const float* __restrict__ g_blend,
                                              const float* __restrict__ b_blend,
                                              const float* __restrict__ x,
                                              char* __restrict__ wsb,
                                              float* __restrict__ ws) {
  const int t = threadIdx.x;
  if (blockIdx.x < 256) {
    __shared__ float tile[32][33];
    int blk = blockIdx.x;
    int b = blk >> 6, by = (blk >> 3) & 7, bx = blk & 7;
    int w0 = bx * 32, h0 = by * 32;
    int txx = t & 31, tyy = t >> 5;
    #pragma unroll
    for (int j = 0; j < 4; ++j) {
      int wi = w0 + tyy + j * 8;
      tile[tyy + j * 8][txx] = noise[(size_t)(b * 256 + wi) * 256 + h0 + txx];
    }
    __syncthreads();
    #pragma unroll
    for (int j = 0; j < 4; ++j) {
      int hi = h0 + tyy + j * 8;
      ws[WS_NT + (size_t)(b * 256 + hi) * 256 + w0 + txx] = tile[txx][tyy + j * 8];
    }
  } else if (blockIdx.x < 408) {
    int m = blockIdx.x - 256;
    int j = m >> 3, r = m & 7, b = r >> 1, half = r & 1;
    int o = half * 256 + t;
    const float4* wrow = (const float4*)(Wfc + ((size_t)j * 512 + o) * 512);
    const float4* srow = (const float4*)(style + ((size_t)b * 19 + j) * 512);
    float acc = 0.f;
    for (int d = 0; d < 128; ++d) {
      float4 w = wrow[d];
      float4 s = srow[d];
      acc = fmaf(w.x, s.x, acc); acc = fmaf(w.y, s.y, acc);
      acc = fmaf(w.z, s.z, acc); acc = fmaf(w.w, s.w, acc);
    }
    acc += bfc[j * 512 + o];
    ws[WS_MU + ((size_t)b * 19 + j) * 512 + o] = fmaxf(acc, 0.f);
  } else if (blockIdx.x < 552) {
    int tid = (blockIdx.x - 408) * 256 + t;
    int lane = tid & 63, grp = tid >> 6;
    int s36 = grp % 36, nb = grp / 36;
    int kk = s36 >> 2, cb = s36 & 3;
    int n = nb * 16 + (lane & 15);
    int conv = n & 1, cout = n >> 1;
    float blend = conv ? b_blend[0] : g_blend[0];
    float scale = 1.f - 1.f / (1.f + __expf(-blend));
    const float* src = conv ? w_b : w_g;
    bf16x8 v;
    #pragma unroll
    for (int i = 0; i < 8; ++i) {
      int k = s36 * 32 + (lane >> 4) * 8 + i;
      int kki = k >> 7, cin = k & 127;
      v[i] = (short)f2bf(scale * src[((size_t)cout * 128 + cin) * 9 + kki]);
    }
    size_t slot = (size_t)(kk * 5 + cb) * 16384 + (size_t)(nb * 64 + lane) * 16;
    #pragma unroll
    for (int bb2 = 0; bb2 < 4; ++bb2)
      *(bf16x8*)(wsb + WS_BSTG_B + (size_t)bb2 * 45 * 16384 + slot) = v;
  } else if (blockIdx.x < 642) {
    int tid = (blockIdx.x - 552) * 256 + t;
    if (tid < 23040) {
      int l = tid / 1152, r = tid % 1152, k = r >> 7, cin = r & 127;
      float v = (l == 0) ? 0.f : w_sh[((size_t)cin * 19 + (l - 1)) * 9 + k];
      ((unsigned short*)(wsb + WS_WSH_B))[tid] = f2bf(v);
    }
  } else if (blockIdx.x < 1154) {
    // xstats: per (b,c) sums of x and x^2 (noise decoupled algebraically)
    const int bc = blockIdx.x - 642;
    const int c = bc & 127;
    const float4* xp = (const float4*)(x + (size_t)bc * HW);
    float s1 = 0.f, s2 = 0.f;
    for (int i = 0; i < 64; ++i) {
      float4 xv = xp[i * 256 + t];
      s1 += xv.x + xv.y + xv.z + xv.w;
      s2 = fmaf(xv.x, xv.x, s2); s2 = fmaf(xv.y, xv.y, s2);
      s2 = fmaf(xv.z, xv.z, s2); s2 = fmaf(xv.w, xv.w, s2);
    }
    #pragma unroll
    for (int m = 32; m; m >>= 1) { s1 += __shfl_xor(s1, m); s2 += __shfl_xor(s2, m); }
    if ((t & 63) == 0) { atomicAdd(&ws[WS_SUM + c], s1); atomicAdd(&ws[WS_SSQ + c], s2); }
  } else {
    // nstats: scalar sums over the whole noise tensor (262144 floats total:
    // 16 blocks x 16384 floats)
    int blk = blockIdx.x - 1154;               // 0..15
    const float4* np = (const float4*)(noise + (size_t)blk * 16384);
    float s1 = 0.f, s2 = 0.f;
    for (int i = 0; i < 16; ++i) {
      float4 nz = np[i * 256 + t];
      s1 += nz.x + nz.y + nz.z + nz.w;
      s2 = fmaf(nz.x, nz.x, s2); s2 = fmaf(nz.y, nz.y, s2);
      s2 = fmaf(nz.z, nz.z, s2); s2 = fmaf(nz.w, nz.w, s2);
    }
    #pragma unroll
    for (int m = 32; m; m >>= 1) { s1 += __shfl_xor(s1, m); s2 += __shfl_xor(s2, m); }
    if ((t & 63) == 0) { atomicAdd(&ws[WS_S1N], s1); atomicAdd(&ws[WS_S2N], s2); }
  }
}

// ---------------- kprep2: atab only (128 blocks) ------------------------------
__global__ __launch_bounds__(512) void kprep2(const float* __restrict__ w_cg,
                                              const float* __restrict__ w_cb,
                                              float* __restrict__ ws) {
  const int t = threadIdx.x;
  __shared__ float wlds[32 * 288];
  const int blkm = blockIdx.x;             // 0..127
  const int cblk = blkm & 7, ssplit = (blkm >> 3) & 3, b = blkm >> 5;
  const int conv = t / 144, r = t % 144, cl = r / 9, k = r % 9;
  const int c = cblk * 16 + cl;
  const float* mu = ws + WS_MU;
  float acc[19];
  #pragma unroll
  for (int l = 0; l < 19; ++l) acc[l] = 0.f;

  for (int chunk = 0; chunk < 4; ++chunk) {
    const int s0 = ssplit * 128 + chunk * 32;
    for (int i = t; i < 9216; i += 512) {
      int kx = i % 9, q = i / 9, sl = q & 31, cc = q >> 5;
      int cv2 = cc >> 4, cl2 = cc & 15;
      const float* src = cv2 ? w_cb : w_cg;
      float v = src[((size_t)(cblk * 16 + cl2) * 512 + s0 + sl) * 9 + kx];
      wlds[sl * 288 + cv2 * 144 + cl2 * 9 + kx] = v;
    }
    __syncthreads();
    if (t < 288) {
      for (int sl = 0; sl < 32; ++sl) {
        float w = wlds[sl * 288 + t];
        int s = s0 + sl;
        #pragma unroll
        for (int l = 0; l < 19; ++l)
          acc[l] = fmaf(mu[((size_t)b * 19 + l) * 512 + s], w, acc[l]);
      }
    }
    __syncthreads();
  }
  if (t < 288) {
    #pragma unroll
    for (int l = 0; l < 19; ++l)
      atomicAdd(&ws[WS_A2 + (((size_t)b * 19 + l) * 9 + k) * 256 + conv * 128 + c], acc[l]);
  }
}

// ---- kprep3: packoh (144 blocks) + stats-finalize (block 0, noise-decoupled) -
__global__ __launch_bounds__(256) void kprep3(const float* __restrict__ g_blend,
                                              const float* __restrict__ b_blend,
                                              const float* __restrict__ nvar,
                                              char* __restrict__ wsb,
                                              float* __restrict__ ws) {
  if (blockIdx.x == 0 && threadIdx.x < 128) {
    int c = threadIdx.x;
    float s1n = ws[WS_S1N], s2n = ws[WS_S2N];
    float nv = nvar[c];
    float mean = (ws[WS_SUM + c] + nv * s1n) / (float)NRED;
    float ex2 = (ws[WS_SSQ + c] + nv * nv * s2n) / (float)NRED;  // cross ~8e-5, dropped
    float var = ex2 - mean * mean;
    ws[WS_MEAN + c] = mean;
    ws[WS_ISTD + c] = 1.f / sqrtf(var + 1e-5f);
  }
  int tid = blockIdx.x * 256 + threadIdx.x;
  int lane = tid & 63, grp = tid >> 6;
  int kk = grp % 9, nb = (grp / 9) % 16, b = grp / 144;
  int n = nb * 16 + (lane & 15);
  int conv = n & 1, cout = n >> 1;
  float blend = conv ? b_blend[0] : g_blend[0];
  float scale = 1.f / (1.f + __expf(-blend));
  bf16x8 v;
  #pragma unroll
  for (int i = 0; i < 8; ++i) {
    int l = (lane >> 4) * 8 + i;
    float val = 0.f;
    if (l < 19)
      val = scale * ws[WS_A2 + (((size_t)b * 19 + l) * 9 + kk) * 256 + conv * 128 + cout];
    v[i] = (short)f2bf(val);
  }
  *(bf16x8*)(wsb + WS_BSTG_B + ((size_t)b * 45 + kk * 5 + 4) * 16384 +
             (size_t)(nb * 64 + lane) * 16) = v;
}

// ---------------- main fused MFMA kernel (exact R15: 225.5us) ----------------
// grid (16,16,4b), block 1024 (16 waves: 4M x 4N). 45 static phases, 3-ring,
// distance-2 prefetch, 1 barrier/phase, counted vmcnt(1); all ds addr = base
// + imm offset; actv [cg][hp] stride 5200 (16B-aligned).
// LDS: labt 1600 | actv2 83200 | ohA 25920 | small 3072 | bstage 49152 = 162944
__global__ __launch_bounds__(1024, 4) void k_main(
    const float* __restrict__ x, const int* __restrict__ labels,
    const float* __restrict__ b_sh,
    const float* __restrict__ b_g, const float* __restrict__ b_b,
    const float* __restrict__ b_cg, const float* __restrict__ b_cb,
    const float* __restrict__ noise_var,
    const float* __restrict__ g_blend, const float* __restrict__ b_blend,
    const float* __restrict__ ws, float* __restrict__ out) {
  extern __shared__ char smem[];
  int* labt = (int*)smem;                    // [20][20]
  char* actv = smem + 1600;                  // [16 cg][324 hp]x16B, stride 5200
  char* ohA  = smem + 84800;                 // [324][80B] one-hot bf16 (padded)
  float* gbias = (float*)(smem + 110720);
  float* bbias = gbias + 128; float* nvl = gbias + 256;
  float* meanl = gbias + 384; float* istdl = gbias + 512; float* bshl = gbias + 640;
  char* bstg = smem + 113792;                // 3 x 16384 ring

  const int t = threadIdx.x;
  const int b = blockIdx.z;
  const int y0 = blockIdx.y * 16, x0 = blockIdx.x * 16;
  const char* wsb = (const char*)ws;
  const char* wshp = wsb + WS_WSH_B;

  // ---- phase 1: small arrays, label tile, zero ohA ----
  if (t < 128) {
    float ga = 1.f / (1.f + __expf(-g_blend[0]));
    float ba = 1.f / (1.f + __expf(-b_blend[0]));
    gbias[t] = ga * b_cg[t] + (1.f - ga) * b_g[t];
    bbias[t] = ba * b_cb[t] + (1.f - ba) * b_b[t];
    nvl[t] = noise_var[t];
    meanl[t] = ws[WS_MEAN + t];
    istdl[t] = ws[WS_ISTD + t];
    bshl[t] = b_sh[t];
  }
  if (t < 400) {
    int ly = t / 20, lx = t % 20;
    int gy = y0 - 2 + ly, gx = x0 - 2 + lx;
    int v = 0;
    if ((unsigned)gy < 256u && (unsigned)gx < 256u)
      v = labels[((size_t)(b * 256 + gy)) * 256 + gx] + 1;
    labt[t] = v;
  }
  for (int i = t; i < 6480; i += 1024) ((unsigned int*)ohA)[i] = 0u;
  __syncthreads();

  // ---- phase 2: actv tile ([cg][hp] layout) + ohA one-hot ----
  for (int it = t; it < 5184; it += 1024) {      // 324 px * 16 cin-groups
    int hp = it >> 4, cg = it & 15;
    int py = hp / 18, px = hp - py * 18;
    int gy = y0 - 1 + py, gx = x0 - 1 + px;
    int baddr = cg * ASTRIDE + hp * 16;
    bf16x8 o = {0, 0, 0, 0, 0, 0, 0, 0};
    if ((unsigned)gy < 256u && (unsigned)gx < 256u) {
      float accv[8];
      #pragma unroll
      for (int j = 0; j < 8; ++j) accv[j] = bshl[cg * 8 + j];
      #pragma unroll
      for (int k = 0; k < 9; ++k) {
        int dy = k / 3, dx = k - 3 * (k / 3);
        int lv = labt[(py + dy) * 20 + (px + dx)];
        bf16x8 wvv = *(const bf16x8*)(wshp + (size_t)((lv * 9 + k) * 128 + cg * 8) * 2);
        #pragma unroll
        for (int j = 0; j < 8; ++j) accv[j] += bf2f(wvv[j]);
      }
      #pragma unroll
      for (int j = 0; j < 8; ++j) o[j] = (short)f2bf(fmaxf(accv[j], 0.f));
    }
    *(bf16x8*)(actv + baddr) = o;
  }
  if (t < 324) {
    int py = t / 18, px = t - (t / 18) * 18;
    int gy = y0 - 1 + py, gx = x0 - 1 + px;
    if ((unsigned)gy < 256u && (unsigned)gx < 256u) {
      int lv = labt[(py + 1) * 20 + (px + 1)];
      ((unsigned short*)ohA)[t * 40 + (lv - 1)] = 0x3F80;
    }
  }
  __syncthreads();   // full drain: vmcnt==0 entering the K-loop

  // ---- phase 3: 45 static phases, all ds_read = base + imm offset ----
  const int lane = t & 63;
  const int wid = t >> 6;                     // 0..15
  const int wm = wid & 3, wn = wid >> 2;      // 4 M-waves x 4 N-waves
  const int l15 = lane & 15, l16 = lane >> 4;

  const char* abase  = actv + l16 * ASTRIDE + (wm * 4 * 18 + l15) * 16;
  const char* ohbase = ohA + (wm * 4 * 18 + l15) * OHSTRIDE + l16 * 16;
  const char* bbase  = bstg + (wn * 4) * 1024 + lane * 16;
  const char* bsrc = wsb + WS_BSTG_B + (size_t)b * 45 * 16384 + (size_t)t * 16;
  char* ldsd0 = bstg + t * 16;
  char* ldsd1 = ldsd0 + 16384;
  char* ldsd2 = ldsd0 + 32768;

  f32x4 acc[4][4];
  #pragma unroll
  for (int i = 0; i < 4; ++i)
    #pragma unroll
    for (int j = 0; j < 4; ++j) acc[i][j] = (f32x4){0.f, 0.f, 0.f, 0.f};

#define PHASE(CB, KY, KX, RING, NXT, SOFF, DO_STAGE, VMC) { \
  asm volatile("s_waitcnt vmcnt(%0)" :: "i"(VMC) : "memory"); \
  __builtin_amdgcn_s_barrier(); \
  __builtin_amdgcn_sched_barrier(0); \
  if (DO_STAGE) gload_lds16(bsrc + (size_t)(SOFF) * 16384, NXT); \
  bf16x8 bfr_[4]; \
  _Pragma("unroll") \
  for (int nf_ = 0; nf_ < 4; ++nf_) \
    bfr_[nf_] = *(const bf16x8*)(bbase + (RING) * 16384 + nf_ * 1024); \
  bf16x8 af_[4]; \
  _Pragma("unroll") \
  for (int mf_ = 0; mf_ < 4; ++mf_) { \
    if ((CB) < 4) \
      af_[mf_] = *(const bf16x8*)(abase + (CB) * (4 * ASTRIDE) + ((mf_ + (KY)) * 18 + (KX)) * 16); \
    else \
      af_[mf_] = *(const bf16x8*)(ohbase + ((mf_ + (KY)) * 18 + (KX)) * OHSTRIDE); \
  } \
  __builtin_amdgcn_s_setprio(1); \
  _Pragma("unroll") \
  for (int mf_ = 0; mf_ < 4; ++mf_) \
    _Pragma("unroll") \
    for (int nf_ = 0; nf_ < 4; ++nf_) \
      acc[mf_][nf_] = __builtin_amdgcn_mfma_f32_16x16x32_bf16(af_[mf_], bfr_[nf_], acc[mf_][nf_], 0, 0, 0); \
  __builtin_amdgcn_s_setprio(0); }

  // prologue: stage s=0 -> buf0, s=1 -> buf1
  gload_lds16(bsrc, ldsd0);
  gload_lds16(bsrc + 16384, ldsd1);

  // s: CB=s%5, kk=s/5, KY=kk/3, KX=kk%3, RING=s%3, NXT=lds[(s+2)%3]
  PHASE(0, 0, 0, 0, ldsd2,  2, true, 1)   // s=0
  PHASE(1, 0, 0, 1, ldsd0,  3, true, 1)   // s=1
  PHASE(2, 0, 0, 2, ldsd1,  4, true, 1)   // s=2
  PHASE(3, 0, 0, 0, ldsd2,  5, true, 1)   // s=3
  PHASE(4, 0, 0, 1, ldsd0,  6, true, 1)   // s=4
  PHASE(0, 0, 1, 2, ldsd1,  7, true, 1)   // s=5
  PHASE(1, 0, 1, 0, ldsd2,  8, true, 1)   // s=6
  PHASE(2, 0, 1, 1, ldsd0,  9, true, 1)   // s=7
  PHASE(3, 0, 1, 2, ldsd1, 10, true, 1)   // s=8
  PHASE(4, 0, 1, 0, ldsd2, 11, true, 1)   // s=9
  PHASE(0, 0, 2, 1, ldsd0, 12, true, 1)   // s=10
  PHASE(1, 0, 2, 2, ldsd1, 13, true, 1)   // s=11
  PHASE(2, 0, 2, 0, ldsd2, 14, true, 1)   // s=12
  PHASE(3, 0, 2, 1, ldsd0, 15, true, 1)   // s=13
  PHASE(4, 0, 2, 2, ldsd1, 16, true, 1)   // s=14
  PHASE(0, 1, 0, 0, ldsd2, 17, true, 1)   // s=15
  PHASE(1, 1, 0, 1, ldsd0, 18, true, 1)   // s=16
  PHASE(2, 1, 0, 2, ldsd1, 19, true, 1)   // s=17
  PHASE(3, 1, 0, 0, ldsd2, 20, true, 1)   // s=18
  PHASE(4, 1, 0, 1, ldsd0, 21, true, 1)   // s=19
  PHASE(0, 1, 1, 2, ldsd1, 22, true, 1)   // s=20
  PHASE(1, 1, 1, 0, ldsd2, 23, true, 1)   // s=21
  PHASE(2, 1, 1, 1, ldsd0, 24, true, 1)   // s=22
  PHASE(3, 1, 1, 2, ldsd1, 25, true, 1)   // s=23
  PHASE(4, 1, 1, 0, ldsd2, 26, true, 1)   // s=24
  PHASE(0, 1, 2, 1, ldsd0, 27, true, 1)   // s=25
  PHASE(1, 1, 2, 2, ldsd1, 28, true, 1)   // s=26
  PHASE(2, 1, 2, 0, ldsd2, 29, true, 1)   // s=27
  PHASE(3, 1, 2, 1, ldsd0, 30, true, 1)   // s=28
  PHASE(4, 1, 2, 2, ldsd1, 31, true, 1)   // s=29
  PHASE(0, 2, 0, 0, ldsd2, 32, true, 1)   // s=30
  PHASE(1, 2, 0, 1, ldsd0, 33, true, 1)   // s=31
  PHASE(2, 2, 0, 2, ldsd1, 34, true, 1)   // s=32
  PHASE(3, 2, 0, 0, ldsd2, 35, true, 1)   // s=33
  PHASE(4, 2, 0, 1, ldsd0, 36, true, 1)   // s=34
  PHASE(0, 2, 1, 2, ldsd1, 37, true, 1)   // s=35
  PHASE(1, 2, 1, 0, ldsd2, 38, true, 1)   // s=36
  PHASE(2, 2, 1, 1, ldsd0, 39, true, 1)   // s=37
  PHASE(3, 2, 1, 2, ldsd1, 40, true, 1)   // s=38
  PHASE(4, 2, 1, 0, ldsd2, 41, true, 1)   // s=39
  PHASE(0, 2, 2, 1, ldsd0, 42, true, 1)   // s=40
  PHASE(1, 2, 2, 2, ldsd1, 43, true, 1)   // s=41
  PHASE(2, 2, 2, 0, ldsd2, 44, true, 1)   // s=42 (last stage)
  PHASE(3, 2, 2, 1, ldsd0,  0, false, 1)  // s=43
  PHASE(4, 2, 2, 2, ldsd1,  0, false, 0)  // s=44
#undef PHASE

  // ---- epilogue: LDS round-trip per chunk, coalesced x/nt/out traffic ----
  const float* nt = ws + WS_NT + (size_t)b * HW;
  float* eps = (float*)(smem + 1600);          // [64][260] f32 chunk

  #pragma unroll
  for (int chunk = 0; chunk < 4; ++chunk) {
    __syncthreads();
    #pragma unroll
    for (int mf = 0; mf < 4; ++mf) {
      int widx = (wn * 16 + l15) * 260 + (wm * 4 + mf) * 16 + l16 * 4;
      *(f32x4*)(eps + widx) = acc[mf][chunk];
    }
    __syncthreads();
    #pragma unroll
    for (int rep = 0; rep < 2; ++rep) {
      int u = rep * 1024 + t;                 // (ci 32)(y 16)(xq 4)
      int xq = u & 3, y = (u >> 2) & 15, ci = u >> 6;
      int wnp = ci >> 3, qq = ci & 7;
      int c = wnp * 32 + chunk * 8 + qq;
      int rg = wnp * 16 + 2 * qq;
      f32x4 g4 = *(const f32x4*)(eps + rg * 260 + y * 16 + xq * 4);
      f32x4 b4 = *(const f32x4*)(eps + (rg + 1) * 260 + y * 16 + xq * 4);
      const float gb_ = gbias[c], bb_ = bbias[c];
      const float mn = meanl[c], is = istdl[c], nv = nvl[c];
      size_t off = (((size_t)(b * 128 + c)) * 256 + (y0 + y)) * 256 + x0 + xq * 4;
      float4 xv = *(const float4*)(x + off);
      float4 nz = *(const float4*)(nt + (y0 + y) * 256 + x0 + xq * 4);
      float4 o;
      o.x = ((xv.x + nv * nz.x) - mn) * is * (1.f + g4[0] + gb_) + (b4[0] + bb_);
      o.y = ((xv.y + nv * nz.y) - mn) * is * (1.f + g4[1] + gb_) + (b4[1] + bb_);
      o.z = ((xv.z + nv * nz.z) - mn) * is * (1.f + g4[2] + gb_) + (b4[2] + bb_);
      o.w = ((xv.w + nv * nz.w) - mn) * is * (1.f + g4[3] + gb_) + (b4[3] + bb_);
      *(float4*)(out + off) = o;
    }
  }
}

extern "C" void kernel_launch(void* const* d_in, const int* in_sizes, int n_in,
                              void* d_out, int out_size, void* d_ws, size_t ws_size,
                              hipStream_t stream) {
  const float* x        = (const float*)d_in[0];
  const int*   labels   = (const int*)d_in[1];
  const float* noise    = (const float*)d_in[2];
  const float* style    = (const float*)d_in[3];
  const float* nvar     = (const float*)d_in[4];
  const float* w_sh     = (const float*)d_in[5];
  const float* b_sh     = (const float*)d_in[6];
  const float* w_g      = (const float*)d_in[7];
  const float* b_g      = (const float*)d_in[8];
  const float* w_b      = (const float*)d_in[9];
  const float* b_b      = (const float*)d_in[10];
  const float* Wfc      = (const float*)d_in[11];
  const float* bfc      = (const float*)d_in[12];
  const float* w_cg     = (const float*)d_in[13];
  const float* b_cg     = (const float*)d_in[14];
  const float* w_cb     = (const float*)d_in[15];
  const float* b_cb     = (const float*)d_in[16];
  const float* g_blend  = (const float*)d_in[17];
  const float* b_blend  = (const float*)d_in[18];
  float* ws  = (float*)d_ws;
  char*  wsb = (char*)d_ws;
  float* out = (float*)d_out;

  static bool attr_set = false;
  if (!attr_set) {
    (void)hipFuncSetAttribute((const void*)k_main,
                              hipFuncAttributeMaxDynamicSharedMemorySize, 162944);
    attr_set = true;
  }

  hipMemsetAsync((char*)d_ws + (size_t)WS_SUM * 4, 0, 256 * 4, stream);
  hipMemsetAsync((char*)d_ws + (size_t)WS_A2 * 4, 0, (size_t)175106 * 4, stream);

  kprep1<<<dim3(1170), dim3(256), 0, stream>>>(noise, style, Wfc, bfc,
                                               w_g, w_b, w_sh, g_blend, b_blend,
                                               x, wsb, ws);
  kprep2<<<dim3(128), dim3(512), 0, stream>>>(w_cg, w_cb, ws);
  kprep3<<<dim3(144), dim3(256), 0, stream>>>(g_blend, b_blend, nvar, wsb, ws);
  k_main<<<dim3(16, 16, 4), dim3(1024), 162944, stream>>>(
      x, labels, b_sh, b_g, b_b, b_cg, b_cb,
      nvar, g_blend, b_blend, ws, out);
}